// Round 5
// baseline (301.915 us; speedup 1.0000x reference)
//
#include <hip/hip_runtime.h>
#include <hip/hip_bf16.h>
#include <stdint.h>

typedef __bf16 bf16;
typedef __bf16 bf16x8 __attribute__((ext_vector_type(8)));
typedef float floatx4 __attribute__((ext_vector_type(4)));
typedef float floatx8 __attribute__((ext_vector_type(8)));

#define MFMA16(A, B, C) __builtin_amdgcn_mfma_f32_16x16x32_bf16(A, B, C, 0, 0, 0)

constexpr int Sc = 2048, HIDc = 2048, NHc = 32, NKVc = 8, HDc = 64;
constexpr float kScale = 0.125f;   // HD^-0.5
constexpr float kMax = 9.0f;       // static softmax max: |s*scale| <= 8 (|q|=|k|=8)

// async 16B global -> LDS (wave-uniform base + lane*16 on the LDS side)
__device__ __forceinline__ void async16(const bf16* g, bf16* l) {
  __builtin_amdgcn_global_load_lds(
      (const __attribute__((address_space(1))) void*)g,
      (__attribute__((address_space(3))) void*)l, 16, 0, 0);
}

// ---------------------------------------------------------------------------
// f32 -> bf16 conversion for hs + 4 weight matrices (blockIdx.y selects).
// Memory-bound; measured at ~6.3 TB/s (roofline).
// ---------------------------------------------------------------------------
__global__ __launch_bounds__(256)
void cvt5(const float* __restrict__ s0, bf16* __restrict__ d0, int n0,
          const float* __restrict__ s1, bf16* __restrict__ d1, int n1,
          const float* __restrict__ s2, bf16* __restrict__ d2, int n2,
          const float* __restrict__ s3, bf16* __restrict__ d3, int n3,
          const float* __restrict__ s4, bf16* __restrict__ d4, int n4)
{
  const float* s; bf16* d; int n;
  switch (blockIdx.y) {
    case 0: s = s0; d = d0; n = n0; break;
    case 1: s = s1; d = d1; n = n1; break;
    case 2: s = s2; d = d2; n = n2; break;
    case 3: s = s3; d = d3; n = n3; break;
    default: s = s4; d = d4; n = n4; break;
  }
  const size_t stride = (size_t)gridDim.x * blockDim.x * 8;
  for (size_t i = ((size_t)blockIdx.x * blockDim.x + threadIdx.x) * 8;
       i < (size_t)n; i += stride) {
    floatx8 f = *(const floatx8*)(s + i);
    bf16x8 o;
#pragma unroll
    for (int j = 0; j < 8; ++j) o[j] = (bf16)f[j];
    *(bf16x8*)(d + i) = o;
  }
}

// ---------------------------------------------------------------------------
// GEMM body: C(MxN) = A(MxK) @ Bw(NxK)^T, bf16, fp32 accum, async LDS staging.
// 128x128 tile, BK=32, 4 waves (2x2), each wave 64x64 (4x4 MFMA).
// ---------------------------------------------------------------------------
template<bool CF32>
__device__ __forceinline__
void gemm_bt_async(const bf16* __restrict__ A, const bf16* __restrict__ Bw,
                   void* __restrict__ C, int N, int K, int m0, int n0,
                   bf16* As, bf16* Bs)
{
  const int tid  = threadIdx.x;
  const int lane = tid & 63;
  const int w    = tid >> 6;
  const int wm   = (w >> 1) * 64;
  const int wn   = (w & 1) * 64;
  const int r    = lane & 15;
  const int quad = lane >> 4;

  floatx4 acc[4][4] = {};

  const int seg0 = tid, seg1 = tid + 256;
  const bf16* gA0 = A  + (size_t)(m0 + (seg0 >> 2)) * K + (seg0 & 3) * 8;
  const bf16* gA1 = A  + (size_t)(m0 + (seg1 >> 2)) * K + (seg1 & 3) * 8;
  const bf16* gB0 = Bw + (size_t)(n0 + (seg0 >> 2)) * K + (seg0 & 3) * 8;
  const bf16* gB1 = Bw + (size_t)(n0 + (seg1 >> 2)) * K + (seg1 & 3) * 8;
  bf16* lA0 = As + seg0 * 8; bf16* lA1 = As + seg1 * 8;
  bf16* lB0 = Bs + seg0 * 8; bf16* lB1 = Bs + seg1 * 8;

  for (int k0 = 0; k0 < K; k0 += 32) {
    __syncthreads();
    async16(gA0 + k0, lA0);
    async16(gA1 + k0, lA1);
    async16(gB0 + k0, lB0);
    async16(gB1 + k0, lB1);
    __syncthreads();

    bf16x8 af[4], bfr[4];
#pragma unroll
    for (int mt = 0; mt < 4; ++mt)
      af[mt] = *(const bf16x8*)(As + (wm + mt * 16 + r) * 32 + quad * 8);
#pragma unroll
    for (int nt = 0; nt < 4; ++nt)
      bfr[nt] = *(const bf16x8*)(Bs + (wn + nt * 16 + r) * 32 + quad * 8);
#pragma unroll
    for (int mt = 0; mt < 4; ++mt)
#pragma unroll
      for (int nt = 0; nt < 4; ++nt)
        acc[mt][nt] = MFMA16(af[mt], bfr[nt], acc[mt][nt]);
  }

#pragma unroll
  for (int mt = 0; mt < 4; ++mt) {
#pragma unroll
    for (int nt = 0; nt < 4; ++nt) {
      const int row = m0 + wm + mt * 16 + quad * 4;
      const int col = n0 + wn + nt * 16 + r;
#pragma unroll
      for (int reg = 0; reg < 4; ++reg) {
        const size_t ci = (size_t)(row + reg) * N + col;
        const float v = acc[mt][nt][reg];
        if constexpr (CF32) ((float*)C)[ci] = v;
        else                ((bf16*)C)[ci] = (bf16)v;
      }
    }
  }
}

__global__ __launch_bounds__(256, 3)
void qkv_gemm(const bf16* __restrict__ hs,
              const bf16* __restrict__ Wq, const bf16* __restrict__ Wk,
              const bf16* __restrict__ Wv,
              bf16* __restrict__ q_ws, bf16* __restrict__ k_ws,
              bf16* __restrict__ v_ws)
{
  __shared__ bf16 As[128 * 32];
  __shared__ bf16 Bs[128 * 32];
  const int by = blockIdx.y;
  const bf16* Bw; bf16* C; int N, n0;
  if (by < 16)      { Bw = Wq; C = q_ws; N = 2048; n0 = by * 128; }
  else if (by < 20) { Bw = Wk; C = k_ws; N = 512;  n0 = (by - 16) * 128; }
  else              { Bw = Wv; C = v_ws; N = 512;  n0 = (by - 20) * 128; }
  gemm_bt_async<false>(hs, Bw, C, N, HIDc, blockIdx.x * 128, n0, As, Bs);
}

__global__ __launch_bounds__(256, 3)
void o_gemm(const bf16* __restrict__ a_ws, const bf16* __restrict__ Wo,
            float* __restrict__ out)
{
  __shared__ bf16 As[128 * 32];
  __shared__ bf16 Bs[128 * 32];
  gemm_bt_async<true>(a_ws, Wo, out, HIDc, NHc * HDc,
                      blockIdx.x * 128, blockIdx.y * 128, As, Bs);
}

// ---------------------------------------------------------------------------
// Merged K-prep: blocks 0..4095 = RMSNorm+RoPE on K (one block per token);
// blocks 4096..4607 = V transpose tile (XOR-swizzled LDS).
// ---------------------------------------------------------------------------
__global__ __launch_bounds__(256)
void kv_prep(bf16* __restrict__ kk, const float* __restrict__ kw,
             const float* __restrict__ cp, const float* __restrict__ sp,
             const bf16* __restrict__ v, bf16* __restrict__ vt)
{
  __shared__ bf16 Ts[64 * 64];
  const int bix = blockIdx.x;
  if (bix < 4096) {
    const int m = bix;                   // b*S + s
    const int lane = threadIdx.x & 63;   // d
    const int w = threadIdx.x >> 6;
    const float c  = cp[(size_t)m * 64 + lane];
    const float s  = sp[(size_t)m * 64 + lane];
    const float wk = kw[lane];
    for (int h = w; h < NKVc; h += 4) {
      bf16* p = kk + (size_t)m * (NKVc * HDc) + h * HDc + lane;
      float x = (float)*p;
      float ss = x * x;
#pragma unroll
      for (int off = 1; off < 64; off <<= 1) ss += __shfl_xor(ss, off);
      const float rr = rsqrtf(ss * (1.0f / 64.0f) + 1e-6f);
      const float y = wk * x * rr;
      const float partner = __shfl_xor(y, 32);
      const float rot = (lane < 32) ? -partner : partner;
      *p = (bf16)(y * c + rot * s);
    }
  } else {
    const int bi  = bix - 4096;          // (b*8 + kvh)*32 + st
    const int st  = bi & 31;
    const int kvh = (bi >> 5) & 7;
    const int b   = bi >> 8;
    const int tid = threadIdx.x;
    for (int seg = tid; seg < 512; seg += 256) {
      const int sr = seg >> 3, dc = (seg & 7) * 8;
      bf16x8 xv = *(const bf16x8*)(v + (size_t)(b * Sc + st * 64 + sr) * (NKVc * HDc)
                                     + kvh * HDc + dc);
#pragma unroll
      for (int i = 0; i < 8; ++i)
        Ts[(dc + i) * 64 + (sr ^ dc)] = xv[i];
    }
    __syncthreads();
    for (int seg = tid; seg < 512; seg += 256) {
      const int d = seg >> 3, sc = (seg & 7) * 8;
      bf16x8 yv = *(const bf16x8*)(&Ts[d * 64 + (sc ^ (d & 56))]);
      *(bf16x8*)(vt + ((size_t)((b * NKVc + kvh) * 64 + d)) * Sc + st * 64 + sc) = yv;
    }
  }
}

// ---------------------------------------------------------------------------
// Causal flash attention, GQA groups=4, fused Q RMSNorm+RoPE, static-max
// softmax (associative: no running max / alpha rescale). One 64-row q-tile
// per block, 2048 blocks, longest tiles (qt=31) dispatched first. LDS 25.6KB
// -> 6 blocks/CU resident (launch_bounds(256,6)) for latency hiding.
// K/V^T staged via async global->LDS, XOR swizzle on the global address.
// o aliases q (each block reads/writes only its own exclusive Q region).
// ---------------------------------------------------------------------------
__global__ __launch_bounds__(256, 6)
void attn_fwd(const bf16* __restrict__ q, const bf16* __restrict__ k,
              const bf16* __restrict__ vt, bf16* __restrict__ o,
              const float* __restrict__ qw, const float* __restrict__ cp,
              const float* __restrict__ sp)
{
  __shared__ bf16 Ks[64 * 64];
  __shared__ bf16 Vs[64 * 64];        // V^T [d][kv], swizzled
  __shared__ bf16 Ps[4][16 * 72];     // per-wave P round-trip, stride 72

  const int bi  = blockIdx.x;         // qidx*64 + (b*32 + h)
  const int qt  = 31 - (bi >> 6);     // heavy q-tiles dispatch first
  const int h   = bi & 31;
  const int b   = (bi >> 5) & 1;
  const int kvh = h >> 2;
  const int tid = threadIdx.x, lane = tid & 63, w = tid >> 6;
  const int r = lane & 15, quad = lane >> 4;

  // Q load + fused RMSNorm (kScale folded in) + RoPE
  const floatx8 w0 = *(const floatx8*)(qw + quad * 8);
  const floatx8 w1 = *(const floatx8*)(qw + 32 + quad * 8);
  bf16x8 qf0, qf1;
  {
    const int m = b * Sc + qt * 64 + w * 16 + r;
    const bf16* qp = q + (size_t)m * (NHc * HDc) + h * HDc + quad * 8;
    bf16x8 x0 = *(const bf16x8*)qp;
    bf16x8 x1 = *(const bf16x8*)(qp + 32);
    float ss = 0.f;
#pragma unroll
    for (int i = 0; i < 8; ++i)
      ss += (float)x0[i] * (float)x0[i] + (float)x1[i] * (float)x1[i];
    ss += __shfl_xor(ss, 16);
    ss += __shfl_xor(ss, 32);
    const float rq = rsqrtf(ss * (1.0f / 64.0f) + 1e-6f) * kScale;
    const floatx8 c0 = *(const floatx8*)(cp + (size_t)m * 64 + quad * 8);
    const floatx8 c1 = *(const floatx8*)(cp + (size_t)m * 64 + 32 + quad * 8);
    const floatx8 s0 = *(const floatx8*)(sp + (size_t)m * 64 + quad * 8);
    const floatx8 s1 = *(const floatx8*)(sp + (size_t)m * 64 + 32 + quad * 8);
#pragma unroll
    for (int i = 0; i < 8; ++i) {
      const float y0 = (float)x0[i] * rq * w0[i];
      const float y1 = (float)x1[i] * rq * w1[i];
      qf0[i] = (bf16)(y0 * c0[i] - y1 * s0[i]);   // d < 32
      qf1[i] = (bf16)(y1 * c1[i] + y0 * s1[i]);   // d >= 32
    }
  }

  floatx4 accO[4] = {};
  float lsum[4] = {};

  const int kvr = tid >> 3;             // staging row (0..31), +32 for seg1
  const int cA  = (tid & 7) * 8;        // LDS col8 (lane-contiguous dest)
  const int cx  = cA ^ (8 * (kvr & 7)); // swizzle on the GLOBAL side
  const int xk  = 8 * (r & 7);          // read-side XOR

  const bf16* kp = k + (size_t)b * Sc * (NKVc * HDc) + kvh * HDc;
  const bf16* vp = vt + ((size_t)((b * NKVc + kvh) * 64)) * Sc;

  for (int j = 0; j <= qt; ++j) {
    __syncthreads();
    {
      const bf16* kj = kp + (size_t)j * 64 * (NKVc * HDc);
      const bf16* vj = vp + j * 64;
      async16(kj + (size_t)kvr * (NKVc * HDc) + cx, Ks + tid * 8);
      async16(kj + (size_t)(kvr + 32) * (NKVc * HDc) + cx, Ks + (tid + 256) * 8);
      async16(vj + (size_t)kvr * Sc + cx, Vs + tid * 8);
      async16(vj + (size_t)(kvr + 32) * Sc + cx, Vs + (tid + 256) * 8);
    }
    __syncthreads();

    // S = Q K^T (16 x 64 per wave), pre-scaled
    floatx4 sa[4];
#pragma unroll
    for (int nt = 0; nt < 4; ++nt) sa[nt] = floatx4{0.f, 0.f, 0.f, 0.f};
#pragma unroll
    for (int nt = 0; nt < 4; ++nt) {
      const int kv = nt * 16 + r;
      const bf16x8 kb0 = *(const bf16x8*)(&Ks[kv * 64 + ((quad * 8) ^ xk)]);
      const bf16x8 kb1 = *(const bf16x8*)(&Ks[kv * 64 + ((quad * 8 + 32) ^ xk)]);
      sa[nt] = MFMA16(qf0, kb0, sa[nt]);
      sa[nt] = MFMA16(qf1, kb1, sa[nt]);
    }

    // static-max softmax; mask only on the diagonal tile
    const int maskbase = (j == qt) ? (w * 16 + quad * 4) : 1000;
#pragma unroll
    for (int reg = 0; reg < 4; ++reg) {
#pragma unroll
      for (int nt = 0; nt < 4; ++nt) {
        const float p = (nt * 16 + r <= maskbase + reg)
                            ? __expf(sa[nt][reg] - kMax) : 0.f;
        lsum[reg] += p;
        Ps[w][(quad * 4 + reg) * 72 + nt * 16 + r] = (bf16)p;
      }
    }

    const bf16x8 pa0 = *(const bf16x8*)(&Ps[w][r * 72 + quad * 8]);
    const bf16x8 pa1 = *(const bf16x8*)(&Ps[w][r * 72 + 32 + quad * 8]);
#pragma unroll
    for (int dt = 0; dt < 4; ++dt) {
      const int d = dt * 16 + r;
      const bf16x8 vb0 = *(const bf16x8*)(&Vs[d * 64 + ((quad * 8) ^ xk)]);
      const bf16x8 vb1 = *(const bf16x8*)(&Vs[d * 64 + ((quad * 8 + 32) ^ xk)]);
      accO[dt] = MFMA16(pa0, vb0, accO[dt]);
      accO[dt] = MFMA16(pa1, vb1, accO[dt]);
    }
  }

  // epilogue: reduce l across the 16 column-lanes, divide, write
#pragma unroll
  for (int reg = 0; reg < 4; ++reg) {
    float l = lsum[reg];
#pragma unroll
    for (int off = 1; off < 16; off <<= 1) l += __shfl_xor(l, off);
    const float inv = 1.0f / l;
    const size_t row = (size_t)(b * Sc + qt * 64 + w * 16 + quad * 4 + reg);
#pragma unroll
    for (int dt = 0; dt < 4; ++dt)
      o[row * (NHc * HDc) + h * HDc + dt * 16 + r] = (bf16)(accO[dt][reg] * inv);
  }
}

// ---------------------------------------------------------------------------
extern "C" void kernel_launch(void* const* d_in, const int* in_sizes, int n_in,
                              void* d_out, int out_size, void* d_ws, size_t ws_size,
                              hipStream_t stream)
{
  const float* hs = (const float*)d_in[0];
  const float* cp = (const float*)d_in[1];
  const float* sp = (const float*)d_in[2];
  const float* Wq = (const float*)d_in[3];
  const float* Wk = (const float*)d_in[4];
  const float* Wv = (const float*)d_in[5];
  const float* Wo = (const float*)d_in[6];
  const float* qw = (const float*)d_in[7];
  const float* kw = (const float*)d_in[8];
  float* out = (float*)d_out;

  char* ws = (char*)d_ws;
  bf16* q_ws  = (bf16*)ws;                      // 16 MiB
  bf16* k_ws  = (bf16*)(ws + (16u << 20));      // 4 MiB
  bf16* v_ws  = (bf16*)(ws + (20u << 20));      // 4 MiB
  bf16* vt_ws = (bf16*)(ws + (24u << 20));      // 4 MiB
  bf16* hs_b  = (bf16*)(ws + (28u << 20));      // 16 MiB
  bf16* Wq_b  = (bf16*)(ws + (44u << 20));      // 8 MiB
  bf16* Wk_b  = (bf16*)(ws + (52u << 20));      // 2 MiB
  bf16* Wv_b  = (bf16*)(ws + (54u << 20));      // 2 MiB
  bf16* Wo_b  = (bf16*)(ws + (56u << 20));      // 8 MiB -> 64 MiB total
  bf16* a_ws  = q_ws;                           // safe alias (see attn_fwd)

  dim3 blk(256);
  cvt5<<<dim3(256, 5), blk, 0, stream>>>(
      hs, hs_b, 4096 * 2048, Wq, Wq_b, 2048 * 2048, Wk, Wk_b, 512 * 2048,
      Wv, Wv_b, 512 * 2048, Wo, Wo_b, 2048 * 2048);
  qkv_gemm<<<dim3(32, 24), blk, 0, stream>>>(hs_b, Wq_b, Wk_b, Wv_b,
                                             q_ws, k_ws, v_ws);
  kv_prep<<<dim3(4608), blk, 0, stream>>>(k_ws, kw, cp, sp, v_ws, vt_ws);
  attn_fwd<<<dim3(2048), blk, 0, stream>>>(q_ws, k_ws, vt_ws, a_ws, qw, cp, sp);
  o_gemm<<<dim3(32, 16), blk, 0, stream>>>(a_ws, Wo_b, out);
}